// Round 1
// 665.003 us; speedup vs baseline: 1.0161x; 1.0161x over previous
//
#include <hip/hip_runtime.h>
#include <math.h>

#define TPB 256
#define ROW_CHUNKS 32

typedef float v4f __attribute__((ext_vector_type(4)));

// Kernel 1: masked per-segment partial column sums, atomic-free.
// grid: (col_chunks, ROW_CHUNKS, B). Each block owns a private [TPB*4] slice
// of the partials buffer: partials[(b*ROW_CHUNKS + ry)*D + col].
// Row loop unrolled x8 with independent accumulators: 8 global_load_dwordx4
// in flight per thread. Loads are NON-TEMPORAL (nt): the hs stream is
// read-once and 537 MB -- do not allocate in L2/L3, do not evict the dirty
// poison lines the harness's 2 GiB ws fill just left in the hierarchy.
__global__ void __launch_bounds__(TPB) grit_partial_kernel(
    const float* __restrict__ hs,
    const int* __restrict__ plens,
    const int* __restrict__ ilens,
    float* __restrict__ partials,
    int B, int D)
{
    const int b  = blockIdx.z;
    const int ry = blockIdx.y;
    const int plen = plens[b];
    const int ilen = ilens[b];

    // segment start: prefix sum of prompt_lens (wave-uniform, B tiny)
    int start = 0;
    for (int i = 0; i < b; ++i) start += plens[i];

    const int rpc = (plen + ROW_CHUNKS - 1) / ROW_CHUNKS;
    int r_lo = ry * rpc;
    int r_hi = r_lo + rpc;
    if (r_hi > plen) r_hi = plen;
    if (r_lo < ilen) r_lo = ilen;   // mask out instruction tokens

    const int col = (blockIdx.x * TPB + threadIdx.x) * 4;
    if (col >= D) return;

    const v4f z = {0.f, 0.f, 0.f, 0.f};
    v4f a0 = z, a1 = z, a2 = z, a3 = z, a4 = z, a5 = z, a6 = z, a7 = z;

    if (r_lo < r_hi) {
        const size_t stride = (size_t)D * sizeof(float);
        const char* p = (const char*)(hs + (size_t)(start + r_lo) * (size_t)D + col);
        int r = r_lo;
        for (; r + 8 <= r_hi; r += 8) {
            const v4f v0 = __builtin_nontemporal_load((const v4f*)(p));
            const v4f v1 = __builtin_nontemporal_load((const v4f*)(p + stride));
            const v4f v2 = __builtin_nontemporal_load((const v4f*)(p + 2 * stride));
            const v4f v3 = __builtin_nontemporal_load((const v4f*)(p + 3 * stride));
            const v4f v4 = __builtin_nontemporal_load((const v4f*)(p + 4 * stride));
            const v4f v5 = __builtin_nontemporal_load((const v4f*)(p + 5 * stride));
            const v4f v6 = __builtin_nontemporal_load((const v4f*)(p + 6 * stride));
            const v4f v7 = __builtin_nontemporal_load((const v4f*)(p + 7 * stride));
            p += 8 * stride;
            a0 += v0; a1 += v1; a2 += v2; a3 += v3;
            a4 += v4; a5 += v5; a6 += v6; a7 += v7;
        }
        for (; r < r_hi; ++r) {
            a0 += __builtin_nontemporal_load((const v4f*)(p));
            p += stride;
        }
    }

    const v4f t = ((a0 + a1) + (a2 + a3)) + ((a4 + a5) + (a6 + a7));

    // always write (even zeros): ws is poisoned 0xAA before every launch
    *(v4f*)(partials + (size_t)(b * ROW_CHUNKS + ry) * (size_t)D + col) = t;
}

// Kernel 2: reduce 32 chunk-partials, mean, L2 normalize. One block per seq.
__global__ void __launch_bounds__(TPB) grit_finalize_kernel(
    const int* __restrict__ plens,
    const int* __restrict__ ilens,
    const float* __restrict__ partials,
    float* __restrict__ out,
    int D)
{
    const int b = blockIdx.x;
    const float inv = 1.0f / (float)(plens[b] - ilens[b]);

    const float* __restrict__ p = partials + (size_t)b * ROW_CHUNKS * (size_t)D;
    float* __restrict__ o = out + (size_t)b * (size_t)D;

    // pass 1: chunk-reduce to mean, write mean to out, accumulate sumsq
    float sq = 0.f;
    for (int col = threadIdx.x * 4; col < D; col += TPB * 4) {
        v4f s = {0.f, 0.f, 0.f, 0.f};
        #pragma unroll
        for (int ry = 0; ry < ROW_CHUNKS; ++ry) {
            const v4f v = *(const v4f*)(p + (size_t)ry * (size_t)D + col);
            s += v;
        }
        v4f m = s * inv;
        sq += m.x * m.x + m.y * m.y + m.z * m.z + m.w * m.w;
        *(v4f*)(o + col) = m;
    }

    // wave shuffle reduce, then cross-wave via LDS
    #pragma unroll
    for (int off = 32; off > 0; off >>= 1)
        sq += __shfl_down(sq, off, 64);

    __shared__ float wsum[TPB / 64];
    const int lane = threadIdx.x & 63;
    const int wave = threadIdx.x >> 6;
    if (lane == 0) wsum[wave] = sq;
    __syncthreads();

    float total = 0.f;
    #pragma unroll
    for (int w = 0; w < TPB / 64; ++w) total += wsum[w];

    const float invn = 1.0f / fmaxf(sqrtf(total), 1e-12f);

    // pass 2: rescale out in place (L2-hot, 16 KiB per block)
    for (int col = threadIdx.x * 4; col < D; col += TPB * 4) {
        const v4f m = *(const v4f*)(o + col);
        *(v4f*)(o + col) = m * invn;
    }
}

extern "C" void kernel_launch(void* const* d_in, const int* in_sizes, int n_in,
                              void* d_out, int out_size, void* d_ws, size_t ws_size,
                              hipStream_t stream) {
    const float* hs    = (const float*)d_in[0];
    const int*   plens = (const int*)d_in[1];
    const int*   ilens = (const int*)d_in[2];
    float*       out   = (float*)d_out;

    const int B = in_sizes[1];          // 16
    const int D = out_size / B;         // 4096

    float* partials = (float*)d_ws;     // [B*ROW_CHUNKS, D] fp32

    const int col_chunks = (D + TPB * 4 - 1) / (TPB * 4);   // 4
    dim3 grid(col_chunks, ROW_CHUNKS, B);                   // 2048 blocks
    grit_partial_kernel<<<grid, TPB, 0, stream>>>(hs, plens, ilens, partials, B, D);

    grit_finalize_kernel<<<B, TPB, 0, stream>>>(plens, ilens, partials, out, D);
}

// Round 2
// 664.315 us; speedup vs baseline: 1.0171x; 1.0010x over previous
//
#include <hip/hip_runtime.h>
#include <math.h>

#define TPB 256
#define ROW_CHUNKS 64

typedef float v4f __attribute__((ext_vector_type(4)));

// Kernel 1: masked per-segment partial column sums, atomic-free.
// grid: (ROW_CHUNKS, B). Each block owns a contiguous band of rows and reads
// FULL 16 KB rows: per thread, 4 v4f accumulators cover the whole row width
// (col = tid*4 + q*D/4, q=0..3). The block's address stream is one fully
// contiguous 512 KB run -> each DRAM page activated exactly once, in order.
// 2-row unroll keeps 8 global_load_dwordx4 in flight per thread.
__global__ void __launch_bounds__(TPB) grit_partial_kernel(
    const float* __restrict__ hs,
    const int* __restrict__ plens,
    const int* __restrict__ ilens,
    float* __restrict__ partials,
    int B, int D)
{
    const int b    = blockIdx.y;
    const int band = blockIdx.x;
    const int plen = plens[b];
    const int ilen = ilens[b];

    // segment start: prefix sum of prompt_lens (wave-uniform, B tiny)
    int start = 0;
    for (int i = 0; i < b; ++i) start += plens[i];

    const int rpc = (plen + ROW_CHUNKS - 1) / ROW_CHUNKS;
    int r_lo = band * rpc;
    int r_hi = r_lo + rpc;
    if (r_hi > plen) r_hi = plen;
    if (r_lo < ilen) r_lo = ilen;   // mask out instruction tokens

    const v4f z = {0.f, 0.f, 0.f, 0.f};
    v4f a0 = z, a1 = z, a2 = z, a3 = z;

    // quarter-row size in BYTES: (D/4 floats)*4 = D bytes. Row stride = 4*D bytes.
    const size_t qb = (size_t)D;            // bytes per quarter-row
    const size_t rowb = 4 * qb;             // bytes per row

    if (r_lo < r_hi) {
        const char* p = (const char*)(hs + (size_t)(start + r_lo) * (size_t)D)
                        + (size_t)threadIdx.x * 16;
        int r = r_lo;
        for (; r + 2 <= r_hi; r += 2) {
            const v4f v0 = __builtin_nontemporal_load((const v4f*)(p));
            const v4f v1 = __builtin_nontemporal_load((const v4f*)(p + qb));
            const v4f v2 = __builtin_nontemporal_load((const v4f*)(p + 2 * qb));
            const v4f v3 = __builtin_nontemporal_load((const v4f*)(p + 3 * qb));
            const v4f w0 = __builtin_nontemporal_load((const v4f*)(p + rowb));
            const v4f w1 = __builtin_nontemporal_load((const v4f*)(p + rowb + qb));
            const v4f w2 = __builtin_nontemporal_load((const v4f*)(p + rowb + 2 * qb));
            const v4f w3 = __builtin_nontemporal_load((const v4f*)(p + rowb + 3 * qb));
            p += 2 * rowb;
            a0 += v0; a1 += v1; a2 += v2; a3 += v3;
            a0 += w0; a1 += w1; a2 += w2; a3 += w3;
        }
        if (r < r_hi) {
            a0 += __builtin_nontemporal_load((const v4f*)(p));
            a1 += __builtin_nontemporal_load((const v4f*)(p + qb));
            a2 += __builtin_nontemporal_load((const v4f*)(p + 2 * qb));
            a3 += __builtin_nontemporal_load((const v4f*)(p + 3 * qb));
        }
    }

    // always write (even zeros): ws is poisoned 0xAA before every launch
    float* dst = partials + (size_t)(b * ROW_CHUNKS + band) * (size_t)D
                 + (size_t)threadIdx.x * 4;
    const int q = D / 4;                    // floats per quarter-row
    *(v4f*)(dst)         = a0;
    *(v4f*)(dst + q)     = a1;
    *(v4f*)(dst + 2 * q) = a2;
    *(v4f*)(dst + 3 * q) = a3;
}

// Kernel 2: reduce ROW_CHUNKS chunk-partials, mean, L2 normalize. One block/seq.
__global__ void __launch_bounds__(TPB) grit_finalize_kernel(
    const int* __restrict__ plens,
    const int* __restrict__ ilens,
    const float* __restrict__ partials,
    float* __restrict__ out,
    int D)
{
    const int b = blockIdx.x;
    const float inv = 1.0f / (float)(plens[b] - ilens[b]);

    const float* __restrict__ p = partials + (size_t)b * ROW_CHUNKS * (size_t)D;
    float* __restrict__ o = out + (size_t)b * (size_t)D;

    // pass 1: chunk-reduce to mean, write mean to out, accumulate sumsq
    float sq = 0.f;
    for (int col = threadIdx.x * 4; col < D; col += TPB * 4) {
        v4f s = {0.f, 0.f, 0.f, 0.f};
        #pragma unroll 8
        for (int ry = 0; ry < ROW_CHUNKS; ++ry) {
            const v4f v = *(const v4f*)(p + (size_t)ry * (size_t)D + col);
            s += v;
        }
        v4f m = s * inv;
        sq += m.x * m.x + m.y * m.y + m.z * m.z + m.w * m.w;
        *(v4f*)(o + col) = m;
    }

    // wave shuffle reduce, then cross-wave via LDS
    #pragma unroll
    for (int off = 32; off > 0; off >>= 1)
        sq += __shfl_down(sq, off, 64);

    __shared__ float wsum[TPB / 64];
    const int lane = threadIdx.x & 63;
    const int wave = threadIdx.x >> 6;
    if (lane == 0) wsum[wave] = sq;
    __syncthreads();

    float total = 0.f;
    #pragma unroll
    for (int w = 0; w < TPB / 64; ++w) total += wsum[w];

    const float invn = 1.0f / fmaxf(sqrtf(total), 1e-12f);

    // pass 2: rescale out in place (L2-hot, 16 KiB per block)
    for (int col = threadIdx.x * 4; col < D; col += TPB * 4) {
        const v4f m = *(const v4f*)(o + col);
        *(v4f*)(o + col) = m * invn;
    }
}

extern "C" void kernel_launch(void* const* d_in, const int* in_sizes, int n_in,
                              void* d_out, int out_size, void* d_ws, size_t ws_size,
                              hipStream_t stream) {
    const float* hs    = (const float*)d_in[0];
    const int*   plens = (const int*)d_in[1];
    const int*   ilens = (const int*)d_in[2];
    float*       out   = (float*)d_out;

    const int B = in_sizes[1];          // 16
    const int D = out_size / B;         // 4096

    float* partials = (float*)d_ws;     // [B*ROW_CHUNKS, D] fp32 (16 MiB)

    dim3 grid(ROW_CHUNKS, B);           // 1024 blocks, 4/CU, 32 waves/CU
    grit_partial_kernel<<<grid, TPB, 0, stream>>>(hs, plens, ilens, partials, B, D);

    grit_finalize_kernel<<<B, TPB, 0, stream>>>(plens, ilens, partials, out, D);
}